// Round 5
// baseline (658.205 us; speedup 1.0000x reference)
//
#include <hip/hip_runtime.h>
#include <hip/hip_bf16.h>

#define N_NODES 65536
#define N_EDGES 524288
#define DIM 128
#define NGRAPH 64
#define OUTD 10

// ---------------------------------------------------------------------------
// CSR build: histogram -> exclusive scan (2-level) -> atomic-cursor fill
// ---------------------------------------------------------------------------
__global__ void hist_kernel(const int* __restrict__ dst, int* __restrict__ counts) {
    int e = blockIdx.x * 256 + threadIdx.x;
    if (e < N_EDGES) atomicAdd(&counts[dst[e]], 1);
}

__global__ void scanA_kernel(const int* __restrict__ counts, int* __restrict__ offs,
                             int* __restrict__ btot) {
    __shared__ int lds[1024];
    int t = threadIdx.x;
    int base = blockIdx.x * 1024;
    int v = counts[base + t];
    lds[t] = v;
    __syncthreads();
    for (int off = 1; off < 1024; off <<= 1) {
        int y = (t >= off) ? lds[t - off] : 0;
        __syncthreads();
        lds[t] += y;
        __syncthreads();
    }
    offs[base + t] = lds[t] - v;        // block-local exclusive
    if (t == 1023) btot[blockIdx.x] = lds[t];
}

__global__ void scanB_kernel(int* __restrict__ btot) {
    __shared__ int lds[64];
    int t = threadIdx.x;  // 64 threads
    int v = btot[t];
    lds[t] = v;
    __syncthreads();
    for (int off = 1; off < 64; off <<= 1) {
        int y = (t >= off) ? lds[t - off] : 0;
        __syncthreads();
        lds[t] += y;
        __syncthreads();
    }
    btot[t] = lds[t] - v;               // exclusive block offsets
}

__global__ void scanC_kernel(int* __restrict__ offs, const int* __restrict__ btot,
                             int* __restrict__ cursor) {
    int t = blockIdx.x * 1024 + threadIdx.x;
    int v = offs[t] + btot[blockIdx.x];
    offs[t] = v;
    cursor[t] = v;                      // cursor init fused (removes d2d memcpy)
    if (t == 0) offs[N_NODES] = N_EDGES;
}

__global__ void fill_kernel(const int* __restrict__ dst, const int* __restrict__ src,
                            int* __restrict__ cursor, int* __restrict__ csr_src) {
    int e = blockIdx.x * 256 + threadIdx.x;
    if (e < N_EDGES) {
        int d = dst[e];
        int pos = atomicAdd(&cursor[d], 1);
        csr_src[pos] = src[e];
    }
}

// ---------------------------------------------------------------------------
// GEMM v2: C[M,128] = H[M,128] @ W[128,128], fp32.
// BM=64, 256 threads (4 waves). LDS holds ONLY the H tile (32 KiB, XOR-
// swizzled -> conflict-free ds_read_b128). W is read per-k with wave-uniform
// addresses (lane-invariant) -> scalar/broadcast loads from L1/L2.
// Occupancy: 32 KiB LDS -> 5 blocks/CU = 20 waves/CU (vs 8 before).
// Lane owns 1 row x 32 cols: 32 FMA per k vs ~3 cyc LDS per k -> VALU-bound.
// ---------------------------------------------------------------------------
__global__ __launch_bounds__(256) void gemm_kernel(const float* __restrict__ H,
                                                   const float* __restrict__ W,
                                                   float* __restrict__ C) {
    __shared__ float4 Hs4[64 * 32];   // slot(r,c4) = r*32 + (c4 ^ (r&31))
    int tid = threadIdx.x;
    int row0 = blockIdx.x * 64;
    const float4* H4 = (const float4*)(H + (size_t)row0 * DIM);
#pragma unroll
    for (int i = 0; i < 8; ++i) {
        int f = tid + i * 256;          // 0..2047, coalesced global read
        int r = f >> 5, c4 = f & 31;
        Hs4[r * 32 + (c4 ^ (r & 31))] = H4[f];
    }
    __syncthreads();

    int lane = tid & 63;
    int wv = __builtin_amdgcn_readfirstlane(tid >> 6);   // wave id, forced SGPR
    const float4* Wb = (const float4*)W + wv * 8;        // cols wv*32..wv*32+31
    float acc[32] = {};

#pragma unroll
    for (int k0 = 0; k0 < 128; k0 += 4) {
        float4 h4 = Hs4[lane * 32 + ((k0 >> 2) ^ (lane & 31))];
#pragma unroll
        for (int kk = 0; kk < 4; ++kk) {
            float hv = (kk == 0) ? h4.x : (kk == 1) ? h4.y : (kk == 2) ? h4.z : h4.w;
            const float4* Wr = Wb + (size_t)(k0 + kk) * 32;  // wave-uniform addr
#pragma unroll
            for (int j = 0; j < 8; ++j) {
                float4 w = Wr[j];
                acc[j * 4 + 0] += hv * w.x;
                acc[j * 4 + 1] += hv * w.y;
                acc[j * 4 + 2] += hv * w.z;
                acc[j * 4 + 3] += hv * w.w;
            }
        }
    }
    float4* cp = (float4*)(C + (size_t)(row0 + lane) * DIM + wv * 32);
#pragma unroll
    for (int j = 0; j < 8; ++j)
        cp[j] = make_float4(acc[j * 4], acc[j * 4 + 1], acc[j * 4 + 2], acc[j * 4 + 3]);
}

// ---------------------------------------------------------------------------
// Aggregation + bias + ELU: out[n] = elu( sum_{e in in(n)} t[src_e] + b )
// One wave per node; lane holds a float2. 4-edge ILP unroll to cover gather
// latency (avg degree 8 -> 2 rounds of 4 in-flight loads).
// ---------------------------------------------------------------------------
__global__ __launch_bounds__(256) void agg_elu_kernel(const float* __restrict__ t,
                                                      const int* __restrict__ offs,
                                                      const int* __restrict__ csr_src,
                                                      const float* __restrict__ bias,
                                                      float* __restrict__ out) {
    int wave = threadIdx.x >> 6;
    int lane = threadIdx.x & 63;
    int node = blockIdx.x * 4 + wave;
    int e0 = offs[node], e1 = offs[node + 1];
    const float2* tp = (const float2*)t;
    float ax = 0.f, ay = 0.f, bx = 0.f, by = 0.f;
    int e = e0;
    for (; e + 3 < e1; e += 4) {
        int s0 = csr_src[e], s1 = csr_src[e + 1];
        int s2 = csr_src[e + 2], s3 = csr_src[e + 3];
        float2 v0 = tp[(size_t)s0 * 64 + lane];
        float2 v1 = tp[(size_t)s1 * 64 + lane];
        float2 v2 = tp[(size_t)s2 * 64 + lane];
        float2 v3 = tp[(size_t)s3 * 64 + lane];
        ax += v0.x + v1.x; ay += v0.y + v1.y;
        bx += v2.x + v3.x; by += v2.y + v3.y;
    }
    for (; e < e1; ++e) {
        int s0 = csr_src[e];
        float2 v0 = tp[(size_t)s0 * 64 + lane];
        ax += v0.x; ay += v0.y;
    }
    ax += bx; ay += by;
    float2 bv = ((const float2*)bias)[lane];
    float x = ax + bv.x, y = ay + bv.y;
    x = x > 0.f ? x : expm1f(x);
    y = y > 0.f ? y : expm1f(y);
    float2 r; r.x = x; r.y = y;
    ((float2*)out)[(size_t)node * 64 + lane] = r;
}

// ---------------------------------------------------------------------------
// Per-graph mean pooling (graph_ids sorted): run-length accumulate, atomics
// only at run transitions.
// ---------------------------------------------------------------------------
__global__ __launch_bounds__(128) void pool_kernel(const float* __restrict__ h,
                                                   const int* __restrict__ gid,
                                                   float* __restrict__ sums,
                                                   int* __restrict__ gcount) {
    int c = threadIdx.x;                 // 0..127
    int n0 = blockIdx.x * 64;
    int cur = gid[n0];
    float acc = 0.f;
    int cnt = 0;
    for (int i = 0; i < 64; ++i) {
        int n = n0 + i;
        int g = gid[n];
        if (g != cur) {
            atomicAdd(&sums[cur * DIM + c], acc);
            if (c == 0) atomicAdd(&gcount[cur], cnt);
            cur = g; acc = 0.f; cnt = 0;
        }
        acc += h[(size_t)n * DIM + c];
        cnt++;
    }
    atomicAdd(&sums[cur * DIM + c], acc);
    if (c == 0) atomicAdd(&gcount[cur], cnt);
}

__global__ __launch_bounds__(128) void final_kernel(const float* __restrict__ sums,
                                                    const int* __restrict__ gcount,
                                                    const float* __restrict__ Wc,
                                                    const float* __restrict__ bc,
                                                    float* __restrict__ out) {
    __shared__ float hg[DIM];
    int g = blockIdx.x;
    int t = threadIdx.x;
    float cnt = (float)gcount[g];
    cnt = cnt > 1.f ? cnt : 1.f;
    hg[t] = sums[g * DIM + t] / cnt;
    __syncthreads();
    if (t < OUTD) {
        float a = bc[t];
        for (int d = 0; d < DIM; ++d) a += hg[d] * Wc[d * OUTD + t];
        out[g * OUTD + t] = a;
    }
}

// ---------------------------------------------------------------------------
extern "C" void kernel_launch(void* const* d_in, const int* in_sizes, int n_in,
                              void* d_out, int out_size, void* d_ws, size_t ws_size,
                              hipStream_t stream) {
    const float* features = (const float*)d_in[0];
    const int* src = (const int*)d_in[1];
    const int* dst = (const int*)d_in[2];
    const int* gid = (const int*)d_in[3];
    const float* W1 = (const float*)d_in[4];
    const float* b1 = (const float*)d_in[5];
    const float* W2 = (const float*)d_in[6];
    const float* b2 = (const float*)d_in[7];
    const float* W3 = (const float*)d_in[8];
    const float* b3 = (const float*)d_in[9];
    const float* Wc = (const float*)d_in[10];
    const float* bc = (const float*)d_in[11];
    float* out = (float*)d_out;

    // workspace carve-up
    char* ws = (char*)d_ws;
    float* tbuf   = (float*)ws;                 ws += (size_t)N_NODES * DIM * 4;   // 32 MiB
    float* hbuf   = (float*)ws;                 ws += (size_t)N_NODES * DIM * 4;   // 32 MiB
    int*   csr    = (int*)ws;                   ws += (size_t)N_EDGES * 4;
    int*   offs   = (int*)ws;                   ws += (size_t)(N_NODES + 64) * 4;
    int*   counts = (int*)ws;                   ws += (size_t)N_NODES * 4;
    int*   cursor = (int*)ws;                   ws += (size_t)N_NODES * 4;
    int*   btot   = (int*)ws;                   ws += 64 * 4;
    float* sums   = (float*)ws;                 ws += (size_t)NGRAPH * DIM * 4;
    int*   gcount = (int*)ws;                   ws += NGRAPH * 4;

    // --- CSR build ---
    hipMemsetAsync(counts, 0, (size_t)N_NODES * 4, stream);
    hist_kernel<<<N_EDGES / 256, 256, 0, stream>>>(dst, counts);
    scanA_kernel<<<64, 1024, 0, stream>>>(counts, offs, btot);
    scanB_kernel<<<1, 64, 0, stream>>>(btot);
    scanC_kernel<<<64, 1024, 0, stream>>>(offs, btot, cursor);
    fill_kernel<<<N_EDGES / 256, 256, 0, stream>>>(dst, src, cursor, csr);

    // --- 3 GCN layers: t = h @ W ; h' = elu(A @ t + b) ---
    gemm_kernel<<<N_NODES / 64, 256, 0, stream>>>(features, W1, tbuf);
    agg_elu_kernel<<<N_NODES / 4, 256, 0, stream>>>(tbuf, offs, csr, b1, hbuf);
    gemm_kernel<<<N_NODES / 64, 256, 0, stream>>>(hbuf, W2, tbuf);
    agg_elu_kernel<<<N_NODES / 4, 256, 0, stream>>>(tbuf, offs, csr, b2, hbuf);
    gemm_kernel<<<N_NODES / 64, 256, 0, stream>>>(hbuf, W3, tbuf);
    agg_elu_kernel<<<N_NODES / 4, 256, 0, stream>>>(tbuf, offs, csr, b3, hbuf);

    // --- pooling + classifier ---
    hipMemsetAsync(sums, 0, (size_t)(NGRAPH * DIM * 4 + NGRAPH * 4), stream);
    pool_kernel<<<N_NODES / 64, 128, 0, stream>>>(hbuf, gid, sums, gcount);
    final_kernel<<<NGRAPH, 128, 0, stream>>>(sums, gcount, Wc, bc, out);
}

// Round 7
// 407.714 us; speedup vs baseline: 1.6144x; 1.6144x over previous
//
#include <hip/hip_runtime.h>
#include <hip/hip_bf16.h>

#define N_NODES 65536
#define N_EDGES 524288
#define DIM 128
#define NGRAPH 64
#define OUTD 10

// ---------------------------------------------------------------------------
// CSR build: histogram -> exclusive scan (2-level) -> atomic-cursor fill
// ---------------------------------------------------------------------------
__global__ void hist_kernel(const int* __restrict__ dst, int* __restrict__ counts) {
    int e = blockIdx.x * 256 + threadIdx.x;
    if (e < N_EDGES) atomicAdd(&counts[dst[e]], 1);
}

__global__ void scanA_kernel(const int* __restrict__ counts, int* __restrict__ offs,
                             int* __restrict__ btot) {
    __shared__ int lds[1024];
    int t = threadIdx.x;
    int base = blockIdx.x * 1024;
    int v = counts[base + t];
    lds[t] = v;
    __syncthreads();
    for (int off = 1; off < 1024; off <<= 1) {
        int y = (t >= off) ? lds[t - off] : 0;
        __syncthreads();
        lds[t] += y;
        __syncthreads();
    }
    offs[base + t] = lds[t] - v;        // block-local exclusive
    if (t == 1023) btot[blockIdx.x] = lds[t];
}

__global__ void scanB_kernel(int* __restrict__ btot) {
    __shared__ int lds[64];
    int t = threadIdx.x;  // 64 threads
    int v = btot[t];
    lds[t] = v;
    __syncthreads();
    for (int off = 1; off < 64; off <<= 1) {
        int y = (t >= off) ? lds[t - off] : 0;
        __syncthreads();
        lds[t] += y;
        __syncthreads();
    }
    btot[t] = lds[t] - v;               // exclusive block offsets
}

__global__ void scanC_kernel(int* __restrict__ offs, const int* __restrict__ btot,
                             int* __restrict__ cursor) {
    int t = blockIdx.x * 1024 + threadIdx.x;
    int v = offs[t] + btot[blockIdx.x];
    offs[t] = v;
    cursor[t] = v;                      // cursor init fused (removes d2d memcpy)
    if (t == 0) offs[N_NODES] = N_EDGES;
}

__global__ void fill_kernel(const int* __restrict__ dst, const int* __restrict__ src,
                            int* __restrict__ cursor, int* __restrict__ csr_src) {
    int e = blockIdx.x * 256 + threadIdx.x;
    if (e < N_EDGES) {
        int d = dst[e];
        int pos = atomicAdd(&cursor[d], 1);
        csr_src[pos] = src[e];
    }
}

// ---------------------------------------------------------------------------
// GEMM v3: C[M,128] = H[M,128] @ W[128,128], fp32.
// Block = 128 rows x 128 cols, 256 threads, thread tile 8x8 (fat tile: 64 FMA
// per 2 LDS b128 reads; W/H LDS reads are 4/16-way lane-broadcast -> cheap).
// K is split into two 64-wide halves so LDS = W-half 32KB + H-half 32KB =
// 64 KiB -> 2 blocks/CU co-resident: one block's stage/barrier overlaps the
// other's FMA stream (fix for R1's serial stage->sync->compute @ 1 block/CU).
// W stored as even/odd f4 arrays (2-way bank alias = free); H swizzled with
// c4 ^ ((r>>1)&15) (conflict-free writes, 2-way reads).
// acc[8][8] persists in VGPR across the two k-halves.
// ---------------------------------------------------------------------------
__global__ __launch_bounds__(256, 2) void gemm_kernel(const float* __restrict__ H,
                                                      const float* __restrict__ W,
                                                      float* __restrict__ C) {
    __shared__ float4 Hs[128 * 16];   // H[r][c4] at [r*16 + (c4 ^ ((r>>1)&15))]
    __shared__ float4 Ws0[64 * 16];   // W[k][f4 col 2j]   at [k*16 + j]
    __shared__ float4 Ws1[64 * 16];   // W[k][f4 col 2j+1] at [k*16 + j]
    int tid = threadIdx.x;
    int row0 = blockIdx.x * 128;
    int rg = tid >> 4;                // 0..15 -> rows rg*8 .. rg*8+7
    int cg = tid & 15;                // 0..15 -> cols cg*8 .. cg*8+7

    const float4* H4 = (const float4*)H;
    const float4* W4 = (const float4*)W;
    float acc[8][8] = {};

    for (int kh = 0; kh < 2; ++kh) {
        // --- stage H half-tile: 128 rows x 16 f4 (32 KiB), coalesced ---
#pragma unroll
        for (int i = 0; i < 8; ++i) {
            int f = tid + i * 256;        // 0..2047
            int r = f >> 4, c4 = f & 15;
            Hs[r * 16 + (c4 ^ ((r >> 1) & 15))] =
                H4[(size_t)(row0 + r) * 32 + kh * 16 + c4];
        }
        // --- stage W half: 64 k-rows x 32 f4 (32 KiB), even/odd split ---
#pragma unroll
        for (int i = 0; i < 8; ++i) {
            int f = tid + i * 256;        // 0..2047
            int k = f >> 5, c4 = f & 31;
            float4 v = W4[(size_t)(kh * 64 + k) * 32 + c4];
            if (c4 & 1) Ws1[k * 16 + (c4 >> 1)] = v;
            else        Ws0[k * 16 + (c4 >> 1)] = v;
        }
        __syncthreads();

#pragma unroll 2
        for (int k0 = 0; k0 < 64; k0 += 4) {
            float4 h[8];
#pragma unroll
            for (int i = 0; i < 8; ++i) {
                int r = rg * 8 + i;
                h[i] = Hs[r * 16 + ((k0 >> 2) ^ ((r >> 1) & 15))];
            }
#pragma unroll
            for (int kk = 0; kk < 4; ++kk) {
                float4 w0 = Ws0[(k0 + kk) * 16 + cg];
                float4 w1 = Ws1[(k0 + kk) * 16 + cg];
#pragma unroll
                for (int i = 0; i < 8; ++i) {
                    float hv = (kk == 0) ? h[i].x : (kk == 1) ? h[i].y
                             : (kk == 2) ? h[i].z : h[i].w;
                    acc[i][0] += hv * w0.x; acc[i][1] += hv * w0.y;
                    acc[i][2] += hv * w0.z; acc[i][3] += hv * w0.w;
                    acc[i][4] += hv * w1.x; acc[i][5] += hv * w1.y;
                    acc[i][6] += hv * w1.z; acc[i][7] += hv * w1.w;
                }
            }
        }
        __syncthreads();
    }

#pragma unroll
    for (int i = 0; i < 8; ++i) {
        float* cp = C + (size_t)(row0 + rg * 8 + i) * DIM + cg * 8;
        *(float4*)cp       = make_float4(acc[i][0], acc[i][1], acc[i][2], acc[i][3]);
        *(float4*)(cp + 4) = make_float4(acc[i][4], acc[i][5], acc[i][6], acc[i][7]);
    }
}

// ---------------------------------------------------------------------------
// Aggregation + bias + ELU: out[n] = elu( sum_{e in in(n)} t[src_e] + b )
// One wave per node; lane holds a float2. 4-edge ILP unroll to cover gather
// latency (avg degree 8 -> 2 rounds of 4 in-flight loads).
// ---------------------------------------------------------------------------
__global__ __launch_bounds__(256) void agg_elu_kernel(const float* __restrict__ t,
                                                      const int* __restrict__ offs,
                                                      const int* __restrict__ csr_src,
                                                      const float* __restrict__ bias,
                                                      float* __restrict__ out) {
    int wave = threadIdx.x >> 6;
    int lane = threadIdx.x & 63;
    int node = blockIdx.x * 4 + wave;
    int e0 = offs[node], e1 = offs[node + 1];
    const float2* tp = (const float2*)t;
    float ax = 0.f, ay = 0.f, bx = 0.f, by = 0.f;
    int e = e0;
    for (; e + 3 < e1; e += 4) {
        int s0 = csr_src[e], s1 = csr_src[e + 1];
        int s2 = csr_src[e + 2], s3 = csr_src[e + 3];
        float2 v0 = tp[(size_t)s0 * 64 + lane];
        float2 v1 = tp[(size_t)s1 * 64 + lane];
        float2 v2 = tp[(size_t)s2 * 64 + lane];
        float2 v3 = tp[(size_t)s3 * 64 + lane];
        ax += v0.x + v1.x; ay += v0.y + v1.y;
        bx += v2.x + v3.x; by += v2.y + v3.y;
    }
    for (; e < e1; ++e) {
        int s0 = csr_src[e];
        float2 v0 = tp[(size_t)s0 * 64 + lane];
        ax += v0.x; ay += v0.y;
    }
    ax += bx; ay += by;
    float2 bv = ((const float2*)bias)[lane];
    float x = ax + bv.x, y = ay + bv.y;
    x = x > 0.f ? x : expm1f(x);
    y = y > 0.f ? y : expm1f(y);
    float2 r; r.x = x; r.y = y;
    ((float2*)out)[(size_t)node * 64 + lane] = r;
}

// ---------------------------------------------------------------------------
// Per-graph mean pooling (graph_ids sorted): run-length accumulate, atomics
// only at run transitions.
// ---------------------------------------------------------------------------
__global__ __launch_bounds__(128) void pool_kernel(const float* __restrict__ h,
                                                   const int* __restrict__ gid,
                                                   float* __restrict__ sums,
                                                   int* __restrict__ gcount) {
    int c = threadIdx.x;                 // 0..127
    int n0 = blockIdx.x * 64;
    int cur = gid[n0];
    float acc = 0.f;
    int cnt = 0;
    for (int i = 0; i < 64; ++i) {
        int n = n0 + i;
        int g = gid[n];
        if (g != cur) {
            atomicAdd(&sums[cur * DIM + c], acc);
            if (c == 0) atomicAdd(&gcount[cur], cnt);
            cur = g; acc = 0.f; cnt = 0;
        }
        acc += h[(size_t)n * DIM + c];
        cnt++;
    }
    atomicAdd(&sums[cur * DIM + c], acc);
    if (c == 0) atomicAdd(&gcount[cur], cnt);
}

__global__ __launch_bounds__(128) void final_kernel(const float* __restrict__ sums,
                                                    const int* __restrict__ gcount,
                                                    const float* __restrict__ Wc,
                                                    const float* __restrict__ bc,
                                                    float* __restrict__ out) {
    __shared__ float hg[DIM];
    int g = blockIdx.x;
    int t = threadIdx.x;
    float cnt = (float)gcount[g];
    cnt = cnt > 1.f ? cnt : 1.f;
    hg[t] = sums[g * DIM + t] / cnt;
    __syncthreads();
    if (t < OUTD) {
        float a = bc[t];
        for (int d = 0; d < DIM; ++d) a += hg[d] * Wc[d * OUTD + t];
        out[g * OUTD + t] = a;
    }
}

// ---------------------------------------------------------------------------
extern "C" void kernel_launch(void* const* d_in, const int* in_sizes, int n_in,
                              void* d_out, int out_size, void* d_ws, size_t ws_size,
                              hipStream_t stream) {
    const float* features = (const float*)d_in[0];
    const int* src = (const int*)d_in[1];
    const int* dst = (const int*)d_in[2];
    const int* gid = (const int*)d_in[3];
    const float* W1 = (const float*)d_in[4];
    const float* b1 = (const float*)d_in[5];
    const float* W2 = (const float*)d_in[6];
    const float* b2 = (const float*)d_in[7];
    const float* W3 = (const float*)d_in[8];
    const float* b3 = (const float*)d_in[9];
    const float* Wc = (const float*)d_in[10];
    const float* bc = (const float*)d_in[11];
    float* out = (float*)d_out;

    // workspace carve-up
    char* ws = (char*)d_ws;
    float* tbuf   = (float*)ws;                 ws += (size_t)N_NODES * DIM * 4;   // 32 MiB
    float* hbuf   = (float*)ws;                 ws += (size_t)N_NODES * DIM * 4;   // 32 MiB
    int*   csr    = (int*)ws;                   ws += (size_t)N_EDGES * 4;
    int*   offs   = (int*)ws;                   ws += (size_t)(N_NODES + 64) * 4;
    int*   counts = (int*)ws;                   ws += (size_t)N_NODES * 4;
    int*   cursor = (int*)ws;                   ws += (size_t)N_NODES * 4;
    int*   btot   = (int*)ws;                   ws += 64 * 4;
    float* sums   = (float*)ws;                 ws += (size_t)NGRAPH * DIM * 4;
    int*   gcount = (int*)ws;                   ws += NGRAPH * 4;

    // --- CSR build ---
    hipMemsetAsync(counts, 0, (size_t)N_NODES * 4, stream);
    hist_kernel<<<N_EDGES / 256, 256, 0, stream>>>(dst, counts);
    scanA_kernel<<<64, 1024, 0, stream>>>(counts, offs, btot);
    scanB_kernel<<<1, 64, 0, stream>>>(btot);
    scanC_kernel<<<64, 1024, 0, stream>>>(offs, btot, cursor);
    fill_kernel<<<N_EDGES / 256, 256, 0, stream>>>(dst, src, cursor, csr);

    // --- 3 GCN layers: t = h @ W ; h' = elu(A @ t + b) ---
    gemm_kernel<<<N_NODES / 128, 256, 0, stream>>>(features, W1, tbuf);
    agg_elu_kernel<<<N_NODES / 4, 256, 0, stream>>>(tbuf, offs, csr, b1, hbuf);
    gemm_kernel<<<N_NODES / 128, 256, 0, stream>>>(hbuf, W2, tbuf);
    agg_elu_kernel<<<N_NODES / 4, 256, 0, stream>>>(tbuf, offs, csr, b2, hbuf);
    gemm_kernel<<<N_NODES / 128, 256, 0, stream>>>(hbuf, W3, tbuf);
    agg_elu_kernel<<<N_NODES / 4, 256, 0, stream>>>(tbuf, offs, csr, b3, hbuf);

    // --- pooling + classifier ---
    hipMemsetAsync(sums, 0, (size_t)(NGRAPH * DIM * 4 + NGRAPH * 4), stream);
    pool_kernel<<<N_NODES / 64, 128, 0, stream>>>(hbuf, gid, sums, gcount);
    final_kernel<<<NGRAPH, 128, 0, stream>>>(sums, gcount, Wc, bc, out);
}